// Round 2
// baseline (148.189 us; speedup 1.0000x reference)
//
#include <hip/hip_runtime.h>
#include <hip/hip_bf16.h>

typedef short short8 __attribute__((ext_vector_type(8)));
typedef float f32x4 __attribute__((ext_vector_type(4)));

__device__ __forceinline__ ushort f2bf(float f) {
    union { float f; unsigned u; } v; v.f = f;
    unsigned r = v.u + 0x7fff + ((v.u >> 16) & 1);
    return (ushort)(r >> 16);
}

__device__ __forceinline__ void gload_lds16(const void* g, void* l) {
    __builtin_amdgcn_global_load_lds((const __attribute__((address_space(1))) void*)g,
                                     (__attribute__((address_space(3))) void*)l, 16, 0, 0);
}

// ---------------- prep kernels ----------------

__global__ void conv_bf16_k(const float* __restrict__ in, ushort* __restrict__ out, int n4) {
    int i = blockIdx.x * blockDim.x + threadIdx.x;
    int stride = gridDim.x * blockDim.x;
    for (int j = i; j < n4; j += stride) {
        float4 v = ((const float4*)in)[j];
        ushort4 o;
        o.x = f2bf(v.x); o.y = f2bf(v.y); o.z = f2bf(v.z); o.w = f2bf(v.w);
        ((ushort4*)out)[j] = o;
    }
}

// W [K][N] row-major f32  ->  Wt [N][K] row-major bf16
__global__ void transpose_w_k(const float* __restrict__ W, ushort* __restrict__ Wt, int K, int N) {
    int id = blockIdx.x * blockDim.x + threadIdx.x;
    if (id >= K * N) return;
    int n = id / K, k = id % K;
    Wt[(size_t)n * K + k] = f2bf(W[(size_t)k * N + n]);
}

__global__ void cumsum_k(const int* __restrict__ nnodes, const int* __restrict__ ncand,
                         int* __restrict__ noff, int* __restrict__ eoff, int G) {
    if (threadIdx.x == 0 && blockIdx.x == 0) {
        int a = 0, b = 0;
        for (int g = 0; g < G; g++) {
            noff[g] = a; a += nnodes[g];
            eoff[g] = b; b += ncand[g];
        }
        noff[G] = a; eoff[G] = b;
    }
}

__global__ void index_k(const int* __restrict__ ec, const int* __restrict__ noff,
                        const int* __restrict__ eoff, int G, int E,
                        int* __restrict__ idx, float* __restrict__ out_idx) {
    int e = blockIdx.x * blockDim.x + threadIdx.x;
    if (e >= E) return;
    int lo = 0, hi = G;
    while (hi - lo > 1) {
        int mid = (lo + hi) >> 1;
        if (eoff[mid] <= e) lo = mid; else hi = mid;
    }
    int off = noff[lo];
    int g0 = ec[2 * e] + off, g1 = ec[2 * e + 1] + off;
    idx[2 * e] = g0; idx[2 * e + 1] = g1;
    out_idx[2 * e] = (float)g0; out_idx[2 * e + 1] = (float)g1;
}

// ---------------- GEMM: out[M][N](bf16) = act(A[M][K](bf16) @ Bt[N][K]^T + bias) ----------------
// BM=128, BN=128, BK=64, 256 threads (4 waves, 2x2 of 64x64), mfma 16x16x32 bf16.
// GATHER: A row e is concat(x[idx[e][0]], x[idx[e][1]]), each Dx elems.

template<bool GATHER, bool RELU>
__global__ __launch_bounds__(256) void gemm_k(
    const ushort* __restrict__ A, const ushort* __restrict__ xg,
    const int* __restrict__ idx, const ushort* __restrict__ Bt,
    const float* __restrict__ bias, ushort* __restrict__ out,
    int K, int N, int NT_N, int Dx)
{
    __shared__ __align__(16) ushort Alds[128 * 64];
    __shared__ __align__(16) ushort Blds[128 * 64];

    const int tid = threadIdx.x;
    const int w = tid >> 6, l = tid & 63;
    const int lhi = l >> 4, llo = l & 15;
    const int mt = blockIdx.x / NT_N, nt = blockIdx.x % NT_N;
    const int m0 = mt * 128, n0 = nt * 128;
    const int crow = tid >> 3;        // 0..31 row within a 32-row issue group
    const int kc = (tid & 7) * 8;     // element offset within BK window

    const ushort* ga0[4]; const ushort* ga1[4]; const ushort* gA[4];
#pragma unroll
    for (int i = 0; i < 4; i++) {
        int row = m0 + i * 32 + crow;
        if (GATHER) {
            ga0[i] = xg + (size_t)idx[2 * row + 0] * Dx;
            ga1[i] = xg + (size_t)idx[2 * row + 1] * Dx;
        } else {
            gA[i] = A + (size_t)row * K;
        }
    }
    const ushort* gB[4];
#pragma unroll
    for (int i = 0; i < 4; i++) gB[i] = Bt + (size_t)(n0 + i * 32 + crow) * K;

    f32x4 acc[4][4];
#pragma unroll
    for (int i = 0; i < 4; i++)
#pragma unroll
        for (int j = 0; j < 4; j++) acc[i][j] = {0.f, 0.f, 0.f, 0.f};

    const int wm = w >> 1, wn = w & 1;

    for (int k0 = 0; k0 < K; k0 += 64) {
#pragma unroll
        for (int i = 0; i < 4; i++) {
            const ushort* src;
            if (GATHER) {
                const ushort* base = (k0 & 256) ? ga1[i] : ga0[i];
                src = base + (k0 & 255) + kc;
            } else {
                src = gA[i] + k0 + kc;
            }
            gload_lds16(src, &Alds[(i * 256 + w * 64) * 8]);
        }
#pragma unroll
        for (int i = 0; i < 4; i++) {
            gload_lds16(gB[i] + k0 + kc, &Blds[(i * 256 + w * 64) * 8]);
        }
        __syncthreads();
#pragma unroll
        for (int kk = 0; kk < 2; kk++) {
            short8 a[4], b[4];
#pragma unroll
            for (int f = 0; f < 4; f++)
                a[f] = *(const short8*)&Alds[(wm * 64 + f * 16 + llo) * 64 + kk * 32 + lhi * 8];
#pragma unroll
            for (int f = 0; f < 4; f++)
                b[f] = *(const short8*)&Blds[(wn * 64 + f * 16 + llo) * 64 + kk * 32 + lhi * 8];
#pragma unroll
            for (int mf = 0; mf < 4; mf++)
#pragma unroll
                for (int nf = 0; nf < 4; nf++)
                    acc[mf][nf] = __builtin_amdgcn_mfma_f32_16x16x32_bf16(a[mf], b[nf], acc[mf][nf], 0, 0, 0);
        }
        __syncthreads();
    }

    float bv[4];
#pragma unroll
    for (int nf = 0; nf < 4; nf++) bv[nf] = bias[n0 + wn * 64 + nf * 16 + llo];
#pragma unroll
    for (int mf = 0; mf < 4; mf++) {
        int row = m0 + wm * 64 + mf * 16 + lhi * 4;
#pragma unroll
        for (int q = 0; q < 4; q++) {
#pragma unroll
            for (int nf = 0; nf < 4; nf++) {
                float v = acc[mf][nf][q] + bv[nf];
                if (RELU) v = fmaxf(v, 0.f);
                out[(size_t)(row + q) * N + n0 + wn * 64 + nf * 16 + llo] = f2bf(v);
            }
        }
    }
}

// ---------------- L2 + L3 fused: scores[M][2] = relu(h1@W2^T + b2) @ W3 + b3 ----------------
// BM=128, BN=256 (full H), BK=64, 512 threads (8 waves, 2x4 of 64x64).

__global__ __launch_bounds__(512) void l2_k(
    const ushort* __restrict__ h1, const ushort* __restrict__ Bt,
    const float* __restrict__ bias, const float* __restrict__ W3,
    const float* __restrict__ b3, float* __restrict__ scores, int K)
{
    __shared__ __align__(16) ushort Alds[128 * 64];  // 16KB
    __shared__ __align__(16) ushort Blds[256 * 64];  // 32KB

    const int tid = threadIdx.x;
    const int w = tid >> 6, l = tid & 63;
    const int lhi = l >> 4, llo = l & 15;
    const int m0 = blockIdx.x * 128;
    const int crow = tid >> 3;     // 0..63
    const int kc = (tid & 7) * 8;
    const int wm = w >> 2, wn = w & 3;

    f32x4 acc[4][4];
#pragma unroll
    for (int i = 0; i < 4; i++)
#pragma unroll
        for (int j = 0; j < 4; j++) acc[i][j] = {0.f, 0.f, 0.f, 0.f};

    for (int k0 = 0; k0 < K; k0 += 64) {
#pragma unroll
        for (int i = 0; i < 2; i++) {
            int row = m0 + i * 64 + crow;
            gload_lds16(h1 + (size_t)row * K + k0 + kc, &Alds[(i * 512 + w * 64) * 8]);
        }
#pragma unroll
        for (int i = 0; i < 4; i++) {
            int n = i * 64 + crow;
            gload_lds16(Bt + (size_t)n * K + k0 + kc, &Blds[(i * 512 + w * 64) * 8]);
        }
        __syncthreads();
#pragma unroll
        for (int kk = 0; kk < 2; kk++) {
            short8 a[4], b[4];
#pragma unroll
            for (int f = 0; f < 4; f++)
                a[f] = *(const short8*)&Alds[(wm * 64 + f * 16 + llo) * 64 + kk * 32 + lhi * 8];
#pragma unroll
            for (int f = 0; f < 4; f++)
                b[f] = *(const short8*)&Blds[(wn * 64 + f * 16 + llo) * 64 + kk * 32 + lhi * 8];
#pragma unroll
            for (int mf = 0; mf < 4; mf++)
#pragma unroll
                for (int nf = 0; nf < 4; nf++)
                    acc[mf][nf] = __builtin_amdgcn_mfma_f32_16x16x32_bf16(a[mf], b[nf], acc[mf][nf], 0, 0, 0);
        }
        __syncthreads();
    }

    float b2v[4], w3v0[4], w3v1[4];
#pragma unroll
    for (int nf = 0; nf < 4; nf++) {
        int col = wn * 64 + nf * 16 + llo;
        b2v[nf] = bias[col];
        w3v0[nf] = W3[2 * col + 0];
        w3v1[nf] = W3[2 * col + 1];
    }
    float p0[4][4], p1[4][4];
#pragma unroll
    for (int mf = 0; mf < 4; mf++)
#pragma unroll
        for (int q = 0; q < 4; q++) { p0[mf][q] = 0.f; p1[mf][q] = 0.f; }
#pragma unroll
    for (int mf = 0; mf < 4; mf++)
#pragma unroll
        for (int nf = 0; nf < 4; nf++)
#pragma unroll
            for (int q = 0; q < 4; q++) {
                float v = fmaxf(acc[mf][nf][q] + b2v[nf], 0.f);
                p0[mf][q] += v * w3v0[nf];
                p1[mf][q] += v * w3v1[nf];
            }
    // reduce over the 16-lane column group
#pragma unroll
    for (int m = 1; m < 16; m <<= 1) {
#pragma unroll
        for (int mf = 0; mf < 4; mf++)
#pragma unroll
            for (int q = 0; q < 4; q++) {
                p0[mf][q] += __shfl_xor(p0[mf][q], m);
                p1[mf][q] += __shfl_xor(p1[mf][q], m);
            }
    }
    float* sc = (float*)Alds;  // 4 wn-slices x 128 rows x 2 ens = 4KB, Alds no longer needed
    if (llo == 0) {
#pragma unroll
        for (int mf = 0; mf < 4; mf++)
#pragma unroll
            for (int q = 0; q < 4; q++) {
                int r = wm * 64 + mf * 16 + lhi * 4 + q;
                sc[(wn * 128 + r) * 2 + 0] = p0[mf][q];
                sc[(wn * 128 + r) * 2 + 1] = p1[mf][q];
            }
    }
    __syncthreads();
    if (tid < 256) {
        int row = tid >> 1, j = tid & 1;
        float s = b3[j];
#pragma unroll
        for (int wn2 = 0; wn2 < 4; wn2++) s += sc[(wn2 * 128 + row) * 2 + j];
        scores[(size_t)(m0 + row) * 2 + j] = s;
    }
}

// ---------------- launch ----------------

extern "C" void kernel_launch(void* const* d_in, const int* in_sizes, int n_in,
                              void* d_out, int out_size, void* d_ws, size_t ws_size,
                              hipStream_t stream) {
    const float* node_feat = (const float*)d_in[0];
    const int* edge_candidate = (const int*)d_in[1];
    const int* nnodes = (const int*)d_in[2];
    const int* ncand = (const int*)d_in[3];
    const float* W_enc = (const float*)d_in[4];
    const float* b_enc = (const float*)d_in[5];
    const float* W1 = (const float*)d_in[6];
    const float* b1 = (const float*)d_in[7];
    const float* W2 = (const float*)d_in[8];
    const float* b2 = (const float*)d_in[9];
    const float* W3 = (const float*)d_in[10];
    const float* b3 = (const float*)d_in[11];

    const int D = in_sizes[5];            // 256
    const int H = in_sizes[7];            // 256
    const int ENS = in_sizes[11];         // 2
    const int G = in_sizes[2];            // 64
    const int TOTN = in_sizes[0] / D;     // 32768
    const int E = in_sizes[1] / 2;        // 131072
    const int K1 = 2 * D;                 // 512

    char* wsb = (char*)d_ws;
    size_t off = 0;
    auto alloc = [&](size_t bytes) -> void* {
        void* p = wsb + off;
        off += (bytes + 255) & ~(size_t)255;
        return p;
    };
    ushort* nf_bf = (ushort*)alloc((size_t)TOTN * D * 2);
    ushort* x_bf  = (ushort*)alloc((size_t)TOTN * D * 2);
    ushort* h1    = (ushort*)alloc((size_t)E * H * 2);
    ushort* wtE   = (ushort*)alloc((size_t)D * D * 2);
    ushort* wt1   = (ushort*)alloc((size_t)K1 * H * 2);
    ushort* wt2   = (ushort*)alloc((size_t)H * H * 2);
    int* idxb     = (int*)alloc((size_t)E * 2 * 4);
    int* noff     = (int*)alloc((size_t)(G + 1) * 4);
    int* eoff     = (int*)alloc((size_t)(G + 1) * 4);

    float* scores_out = (float*)d_out;
    float* idx_out = scores_out + (size_t)E * ENS;

    // prep
    conv_bf16_k<<<2048, 256, 0, stream>>>(node_feat, nf_bf, TOTN * D / 4);
    transpose_w_k<<<(D * D + 255) / 256, 256, 0, stream>>>(W_enc, wtE, D, D);
    transpose_w_k<<<(K1 * H + 255) / 256, 256, 0, stream>>>(W1, wt1, K1, H);
    transpose_w_k<<<(H * H + 255) / 256, 256, 0, stream>>>(W2, wt2, H, H);
    cumsum_k<<<1, 64, 0, stream>>>(nnodes, ncand, noff, eoff, G);
    index_k<<<(E + 255) / 256, 256, 0, stream>>>(edge_candidate, noff, eoff, G, E, idxb, idx_out);

    // encoder: x = nf @ W_enc + b_enc
    gemm_k<false, false><<<(TOTN / 128) * (D / 128), 256, 0, stream>>>(
        nf_bf, nullptr, nullptr, wtE, b_enc, x_bf, D, D, D / 128, D);

    // layer 1 (gather fused): h1 = relu(concat(x[i0],x[i1]) @ W1 + b1)
    gemm_k<true, true><<<(E / 128) * (H / 128), 256, 0, stream>>>(
        nullptr, x_bf, idxb, wt1, b1, h1, K1, H, H / 128, D);

    // layer 2 + 3 fused: scores = relu(h1 @ W2 + b2) @ W3 + b3
    l2_k<<<E / 128, 512, 0, stream>>>(h1, wt2, b2, W3, b3, scores_out, H);
}

// Round 3
// 144.534 us; speedup vs baseline: 1.0253x; 1.0253x over previous
//
#include <hip/hip_runtime.h>
#include <hip/hip_bf16.h>

typedef short short8 __attribute__((ext_vector_type(8)));
typedef float f32x4 __attribute__((ext_vector_type(4)));

__device__ __forceinline__ ushort f2bf(float f) {
    union { float f; unsigned u; } v; v.f = f;
    unsigned r = v.u + 0x7fff + ((v.u >> 16) & 1);
    return (ushort)(r >> 16);
}

__device__ __forceinline__ void gload_lds16(const void* g, void* l) {
    __builtin_amdgcn_global_load_lds((const __attribute__((address_space(1))) void*)g,
                                     (__attribute__((address_space(3))) void*)l, 16, 0, 0);
}

// ---------------- prep kernels ----------------

__global__ void conv_bf16_k(const float* __restrict__ in, ushort* __restrict__ out, int n4) {
    int i = blockIdx.x * blockDim.x + threadIdx.x;
    int stride = gridDim.x * blockDim.x;
    for (int j = i; j < n4; j += stride) {
        float4 v = ((const float4*)in)[j];
        ushort4 o;
        o.x = f2bf(v.x); o.y = f2bf(v.y); o.z = f2bf(v.z); o.w = f2bf(v.w);
        ((ushort4*)out)[j] = o;
    }
}

// W [K][N] row-major f32  ->  Wt [N][K] row-major bf16
__global__ void transpose_w_k(const float* __restrict__ W, ushort* __restrict__ Wt, int K, int N) {
    int id = blockIdx.x * blockDim.x + threadIdx.x;
    if (id >= K * N) return;
    int n = id / K, k = id % K;
    Wt[(size_t)n * K + k] = f2bf(W[(size_t)k * N + n]);
}

// per-block prefix scan of nnodes/ncand (G<=256), then global index build
__global__ void index_k(const int* __restrict__ ec,
                        const int* __restrict__ nnodes, const int* __restrict__ ncand,
                        int G, int E,
                        int* __restrict__ idx, float* __restrict__ out_idx) {
    __shared__ int snoff[257];  // exclusive node offsets
    __shared__ int seoff[257];  // inclusive edge cumsum
    if (threadIdx.x == 0) {
        int a = 0, b = 0;
        for (int g = 0; g < G; g++) {
            snoff[g] = a; a += nnodes[g];
            b += ncand[g]; seoff[g] = b;
        }
    }
    __syncthreads();
    int e = blockIdx.x * blockDim.x + threadIdx.x;
    if (e >= E) return;
    int lo = 0, hi = G - 1;
    while (lo < hi) {
        int mid = (lo + hi) >> 1;
        if (seoff[mid] > e) hi = mid; else lo = mid + 1;
    }
    int off = snoff[lo];
    int g0 = ec[2 * e] + off, g1 = ec[2 * e + 1] + off;
    idx[2 * e] = g0; idx[2 * e + 1] = g1;
    out_idx[2 * e] = (float)g0; out_idx[2 * e + 1] = (float)g1;
}

// ---------------- GEMM: out[M][N](bf16) = act(A[M][K](bf16) @ Bt[N][K]^T + bias) ----------------
// BM=128, BN=128, BK=64, 256 threads (4 waves, 2x2 of 64x64), mfma 16x16x32 bf16.
// Double-buffered LDS, prefetch-before-compute, one barrier per K-step.
// MFMA operands swapped -> C^T register layout -> packed dwordx2 stores.
// GATHER: A row e is concat(x[idx[e][0]], x[idx[e][1]]), each Dx elems.

template<bool GATHER, bool RELU>
__global__ __launch_bounds__(256) void gemm_k(
    const ushort* __restrict__ A, const ushort* __restrict__ xg,
    const int* __restrict__ idx, const ushort* __restrict__ Bt,
    const float* __restrict__ bias, ushort* __restrict__ out,
    int K, int N, int NT_N, int Dx)
{
    __shared__ __align__(16) ushort Alds[2][128 * 64];
    __shared__ __align__(16) ushort Blds[2][128 * 64];

    const int tid = threadIdx.x;
    const int w = tid >> 6, l = tid & 63;
    const int lhi = l >> 4, llo = l & 15;
    const int mt = blockIdx.x / NT_N, nt = blockIdx.x % NT_N;
    const int m0 = mt * 128, n0 = nt * 128;
    const int crow = tid >> 3;        // 0..31 row within a 32-row issue group
    const int kc = (tid & 7) * 8;     // element offset within BK window
    const int wm = w >> 1, wn = w & 1;

    const ushort* ga0[4]; const ushort* ga1[4]; const ushort* gA[4];
#pragma unroll
    for (int i = 0; i < 4; i++) {
        int row = m0 + i * 32 + crow;
        if (GATHER) {
            ga0[i] = xg + (size_t)idx[2 * row + 0] * Dx;
            ga1[i] = xg + (size_t)idx[2 * row + 1] * Dx;
        } else {
            gA[i] = A + (size_t)row * K;
        }
    }
    const ushort* gB[4];
#pragma unroll
    for (int i = 0; i < 4; i++) gB[i] = Bt + (size_t)(n0 + i * 32 + crow) * K;

    f32x4 acc[4][4];
#pragma unroll
    for (int i = 0; i < 4; i++)
#pragma unroll
        for (int j = 0; j < 4; j++) acc[i][j] = {0.f, 0.f, 0.f, 0.f};

    const int NK = K >> 6;

    auto stage = [&](int buf, int t) {
        int k0 = t << 6;
#pragma unroll
        for (int i = 0; i < 4; i++) {
            const ushort* src;
            if (GATHER) {
                const ushort* base = (k0 & 256) ? ga1[i] : ga0[i];
                src = base + (k0 & 255) + kc;
            } else {
                src = gA[i] + k0 + kc;
            }
            gload_lds16(src, &Alds[buf][(i * 256 + w * 64) * 8]);
        }
#pragma unroll
        for (int i = 0; i < 4; i++) {
            gload_lds16(gB[i] + k0 + kc, &Blds[buf][(i * 256 + w * 64) * 8]);
        }
    };

    stage(0, 0);
    __syncthreads();          // drains vmcnt: buf0 ready
    int cur = 0;
    for (int t = 0; t < NK; t++) {
        if (t + 1 < NK) stage(cur ^ 1, t + 1);   // prefetch next while computing cur
        const ushort* Ab = Alds[cur];
        const ushort* Bb = Blds[cur];
#pragma unroll
        for (int kk = 0; kk < 2; kk++) {
            short8 a[4], b[4];
#pragma unroll
            for (int f = 0; f < 4; f++)
                a[f] = *(const short8*)&Ab[(wm * 64 + f * 16 + llo) * 64 + kk * 32 + lhi * 8];
#pragma unroll
            for (int f = 0; f < 4; f++)
                b[f] = *(const short8*)&Bb[(wn * 64 + f * 16 + llo) * 64 + kk * 32 + lhi * 8];
#pragma unroll
            for (int mf = 0; mf < 4; mf++)
#pragma unroll
                for (int nf = 0; nf < 4; nf++)
                    acc[mf][nf] = __builtin_amdgcn_mfma_f32_16x16x32_bf16(b[nf], a[mf], acc[mf][nf], 0, 0, 0);
        }
        __syncthreads();      // drains vmcnt(next ready) + lgkm; protects cur^1 overwrite
        cur ^= 1;
    }

    // epilogue: C^T layout -> lane holds 4 consecutive N-cols per frag
    float4 bv4[4];
#pragma unroll
    for (int nf = 0; nf < 4; nf++)
        bv4[nf] = *(const float4*)&bias[n0 + wn * 64 + nf * 16 + lhi * 4];
#pragma unroll
    for (int mf = 0; mf < 4; mf++) {
        int row = m0 + wm * 64 + mf * 16 + llo;
#pragma unroll
        for (int nf = 0; nf < 4; nf++) {
            int colb = n0 + wn * 64 + nf * 16 + lhi * 4;
            float v0 = acc[mf][nf][0] + bv4[nf].x;
            float v1 = acc[mf][nf][1] + bv4[nf].y;
            float v2 = acc[mf][nf][2] + bv4[nf].z;
            float v3 = acc[mf][nf][3] + bv4[nf].w;
            if (RELU) {
                v0 = fmaxf(v0, 0.f); v1 = fmaxf(v1, 0.f);
                v2 = fmaxf(v2, 0.f); v3 = fmaxf(v3, 0.f);
            }
            ushort4 o;
            o.x = f2bf(v0); o.y = f2bf(v1); o.z = f2bf(v2); o.w = f2bf(v3);
            *(ushort4*)&out[(size_t)row * N + colb] = o;
        }
    }
}

// ---------------- L2 + L3 fused: scores[M][2] = relu(h1@W2^T + b2) @ W3 + b3 ----------------
// BM=128, BN=256 (full H), BK=64, 512 threads (8 waves, 2x4 of 64x64). Double-buffered.

__global__ __launch_bounds__(512) void l2_k(
    const ushort* __restrict__ h1, const ushort* __restrict__ Bt,
    const float* __restrict__ bias, const float* __restrict__ W3,
    const float* __restrict__ b3, float* __restrict__ scores, int K)
{
    __shared__ __align__(16) ushort Alds[2][128 * 64];  // 32KB
    __shared__ __align__(16) ushort Blds[2][256 * 64];  // 64KB

    const int tid = threadIdx.x;
    const int w = tid >> 6, l = tid & 63;
    const int lhi = l >> 4, llo = l & 15;
    const int m0 = blockIdx.x * 128;
    const int crow = tid >> 3;     // 0..63
    const int kc = (tid & 7) * 8;
    const int wm = w >> 2, wn = w & 3;

    f32x4 acc[4][4];
#pragma unroll
    for (int i = 0; i < 4; i++)
#pragma unroll
        for (int j = 0; j < 4; j++) acc[i][j] = {0.f, 0.f, 0.f, 0.f};

    const int NK = K >> 6;

    auto stage = [&](int buf, int t) {
        int k0 = t << 6;
#pragma unroll
        for (int i = 0; i < 2; i++) {
            int row = m0 + i * 64 + crow;
            gload_lds16(h1 + (size_t)row * K + k0 + kc, &Alds[buf][(i * 512 + w * 64) * 8]);
        }
#pragma unroll
        for (int i = 0; i < 4; i++) {
            int n = i * 64 + crow;
            gload_lds16(Bt + (size_t)n * K + k0 + kc, &Blds[buf][(i * 512 + w * 64) * 8]);
        }
    };

    stage(0, 0);
    __syncthreads();
    int cur = 0;
    for (int t = 0; t < NK; t++) {
        if (t + 1 < NK) stage(cur ^ 1, t + 1);
        const ushort* Ab = Alds[cur];
        const ushort* Bb = Blds[cur];
#pragma unroll
        for (int kk = 0; kk < 2; kk++) {
            short8 a[4], b[4];
#pragma unroll
            for (int f = 0; f < 4; f++)
                a[f] = *(const short8*)&Ab[(wm * 64 + f * 16 + llo) * 64 + kk * 32 + lhi * 8];
#pragma unroll
            for (int f = 0; f < 4; f++)
                b[f] = *(const short8*)&Bb[(wn * 64 + f * 16 + llo) * 64 + kk * 32 + lhi * 8];
#pragma unroll
            for (int mf = 0; mf < 4; mf++)
#pragma unroll
                for (int nf = 0; nf < 4; nf++)
                    acc[mf][nf] = __builtin_amdgcn_mfma_f32_16x16x32_bf16(b[nf], a[mf], acc[mf][nf], 0, 0, 0);
        }
        __syncthreads();
        cur ^= 1;
    }

    // epilogue: C^T layout. lane holds rows (wm*64+mf*16+llo), cols (wn*64+nf*16+lhi*4 + q).
    // L3 dot: in-lane over (nf,q), cross-lane over lhi via 2 shfl_xor steps.
    float p0[4], p1[4];
#pragma unroll
    for (int mf = 0; mf < 4; mf++) { p0[mf] = 0.f; p1[mf] = 0.f; }
#pragma unroll
    for (int nf = 0; nf < 4; nf++) {
        int colb = wn * 64 + nf * 16 + lhi * 4;
        float4 b2v = *(const float4*)&bias[colb];
        float2 w3a = ((const float2*)W3)[colb + 0];
        float2 w3b = ((const float2*)W3)[colb + 1];
        float2 w3c = ((const float2*)W3)[colb + 2];
        float2 w3d = ((const float2*)W3)[colb + 3];
#pragma unroll
        for (int mf = 0; mf < 4; mf++) {
            float v0 = fmaxf(acc[mf][nf][0] + b2v.x, 0.f);
            float v1 = fmaxf(acc[mf][nf][1] + b2v.y, 0.f);
            float v2 = fmaxf(acc[mf][nf][2] + b2v.z, 0.f);
            float v3 = fmaxf(acc[mf][nf][3] + b2v.w, 0.f);
            p0[mf] += v0 * w3a.x + v1 * w3b.x + v2 * w3c.x + v3 * w3d.x;
            p1[mf] += v0 * w3a.y + v1 * w3b.y + v2 * w3c.y + v3 * w3d.y;
        }
    }
#pragma unroll
    for (int mf = 0; mf < 4; mf++) {
        p0[mf] += __shfl_xor(p0[mf], 16); p1[mf] += __shfl_xor(p1[mf], 16);
        p0[mf] += __shfl_xor(p0[mf], 32); p1[mf] += __shfl_xor(p1[mf], 32);
    }
    float* sc = (float*)Alds;  // 4 wn-slices x 128 rows x 2 ens = 4KB
    if (l < 16) {
#pragma unroll
        for (int mf = 0; mf < 4; mf++) {
            int r = wm * 64 + mf * 16 + l;
            sc[(wn * 128 + r) * 2 + 0] = p0[mf];
            sc[(wn * 128 + r) * 2 + 1] = p1[mf];
        }
    }
    __syncthreads();
    if (tid < 256) {
        int row = tid >> 1, j = tid & 1;
        float s = b3[j];
#pragma unroll
        for (int wn2 = 0; wn2 < 4; wn2++) s += sc[(wn2 * 128 + row) * 2 + j];
        scores[(size_t)(m0 + row) * 2 + j] = s;
    }
}

// ---------------- launch ----------------

extern "C" void kernel_launch(void* const* d_in, const int* in_sizes, int n_in,
                              void* d_out, int out_size, void* d_ws, size_t ws_size,
                              hipStream_t stream) {
    const float* node_feat = (const float*)d_in[0];
    const int* edge_candidate = (const int*)d_in[1];
    const int* nnodes = (const int*)d_in[2];
    const int* ncand = (const int*)d_in[3];
    const float* W_enc = (const float*)d_in[4];
    const float* b_enc = (const float*)d_in[5];
    const float* W1 = (const float*)d_in[6];
    const float* b1 = (const float*)d_in[7];
    const float* W2 = (const float*)d_in[8];
    const float* b2 = (const float*)d_in[9];
    const float* W3 = (const float*)d_in[10];
    const float* b3 = (const float*)d_in[11];

    const int D = in_sizes[5];            // 256
    const int H = in_sizes[7];            // 256
    const int ENS = in_sizes[11];         // 2
    const int G = in_sizes[2];            // 64
    const int TOTN = in_sizes[0] / D;     // 32768
    const int E = in_sizes[1] / 2;        // 131072
    const int K1 = 2 * D;                 // 512

    char* wsb = (char*)d_ws;
    size_t off = 0;
    auto alloc = [&](size_t bytes) -> void* {
        void* p = wsb + off;
        off += (bytes + 255) & ~(size_t)255;
        return p;
    };
    ushort* nf_bf = (ushort*)alloc((size_t)TOTN * D * 2);
    ushort* x_bf  = (ushort*)alloc((size_t)TOTN * D * 2);
    ushort* h1    = (ushort*)alloc((size_t)E * H * 2);
    ushort* wtE   = (ushort*)alloc((size_t)D * D * 2);
    ushort* wt1   = (ushort*)alloc((size_t)K1 * H * 2);
    ushort* wt2   = (ushort*)alloc((size_t)H * H * 2);
    int* idxb     = (int*)alloc((size_t)E * 2 * 4);

    float* scores_out = (float*)d_out;
    float* idx_out = scores_out + (size_t)E * ENS;

    // prep
    conv_bf16_k<<<2048, 256, 0, stream>>>(node_feat, nf_bf, TOTN * D / 4);
    transpose_w_k<<<(D * D + 255) / 256, 256, 0, stream>>>(W_enc, wtE, D, D);
    transpose_w_k<<<(K1 * H + 255) / 256, 256, 0, stream>>>(W1, wt1, K1, H);
    transpose_w_k<<<(H * H + 255) / 256, 256, 0, stream>>>(W2, wt2, H, H);
    index_k<<<(E + 255) / 256, 256, 0, stream>>>(edge_candidate, nnodes, ncand, G, E, idxb, idx_out);

    // encoder: x = nf @ W_enc + b_enc
    gemm_k<false, false><<<(TOTN / 128) * (D / 128), 256, 0, stream>>>(
        nf_bf, nullptr, nullptr, wtE, b_enc, x_bf, D, D, D / 128, D);

    // layer 1 (gather fused): h1 = relu(concat(x[i0],x[i1]) @ W1 + b1)
    gemm_k<true, true><<<(E / 128) * (H / 128), 256, 0, stream>>>(
        nullptr, x_bf, idxb, wt1, b1, h1, K1, H, H / 128, D);

    // layer 2 + 3 fused: scores = relu(h1 @ W2 + b2) @ W3 + b3
    l2_k<<<E / 128, 512, 0, stream>>>(h1, wt2, b2, W3, b3, scores_out, H);
}

// Round 4
// 116.260 us; speedup vs baseline: 1.2746x; 1.2432x over previous
//
#include <hip/hip_runtime.h>
#include <hip/hip_bf16.h>

typedef short short8 __attribute__((ext_vector_type(8)));
typedef float f32x4 __attribute__((ext_vector_type(4)));

__device__ __forceinline__ ushort f2bf(float f) {
    union { float f; unsigned u; } v; v.f = f;
    unsigned r = v.u + 0x7fff + ((v.u >> 16) & 1);
    return (ushort)(r >> 16);
}

__device__ __forceinline__ void gload_lds16(const void* g, void* l) {
    __builtin_amdgcn_global_load_lds((const __attribute__((address_space(1))) void*)g,
                                     (__attribute__((address_space(3))) void*)l, 16, 0, 0);
}

// ---------------- prep kernels ----------------

__global__ void conv_bf16_k(const float* __restrict__ in, ushort* __restrict__ out, int n4) {
    int i = blockIdx.x * blockDim.x + threadIdx.x;
    int stride = gridDim.x * blockDim.x;
    for (int j = i; j < n4; j += stride) {
        float4 v = ((const float4*)in)[j];
        ushort4 o;
        o.x = f2bf(v.x); o.y = f2bf(v.y); o.z = f2bf(v.z); o.w = f2bf(v.w);
        ((ushort4*)out)[j] = o;
    }
}

// W [K][256] row-major f32 -> packed MFMA B-fragments, per-wave-contiguous:
// out[((F*(K/32)+S)*64 + l)*8 + j] = bf16(W[k][n]),  n=F*16+(l&15), k=S*32+(l>>4)*8+j
__global__ void pack_b_k(const float* __restrict__ W, ushort* __restrict__ out, int K) {
    int id = blockIdx.x * blockDim.x + threadIdx.x;
    if (id >= 256 * K) return;
    int j = id & 7;
    int l = (id >> 3) & 63;
    int S = (id >> 9) % (K / 32);
    int F = id / (512 * (K / 32));
    int n = F * 16 + (l & 15);
    int k = S * 32 + (l >> 4) * 8 + j;
    out[id] = f2bf(W[(size_t)k * 256 + n]);
}

// prefix scan of nnodes/ncand in-block (G<=256), then global index build
__global__ void index_k(const int* __restrict__ ec,
                        const int* __restrict__ nnodes, const int* __restrict__ ncand,
                        int G, int E,
                        int* __restrict__ idx, float* __restrict__ out_idx) {
    __shared__ int snoff[257];
    __shared__ int seoff[257];
    if (threadIdx.x == 0) {
        int a = 0, b = 0;
        for (int g = 0; g < G; g++) {
            snoff[g] = a; a += nnodes[g];
            b += ncand[g]; seoff[g] = b;
        }
    }
    __syncthreads();
    int e = blockIdx.x * blockDim.x + threadIdx.x;
    if (e >= E) return;
    int lo = 0, hi = G - 1;
    while (lo < hi) {
        int mid = (lo + hi) >> 1;
        if (seoff[mid] > e) hi = mid; else lo = mid + 1;
    }
    int off = snoff[lo];
    int g0 = ec[2 * e] + off, g1 = ec[2 * e + 1] + off;
    idx[2 * e] = g0; idx[2 * e + 1] = g1;
    out_idx[2 * e] = (float)g0; out_idx[2 * e + 1] = (float)g1;
}

// ---------------- unified MLP GEMM ----------------
// BM=256, BN=256(=N full), BK=64. 512 threads = 8 waves (2 wm x 4 wn), per-wave 128x64.
// A staged via global_load_lds into a 3-deep LDS ring (XOR-swizzled via pre-swizzled src),
// B (weights) packed in global, loaded straight to registers (L2-resident).
// Counted vmcnt(12) at K-tile boundaries: newest staging loads stay in flight (T4).
// MFMA operands swapped -> C^T register layout.

#define LOADB(bk, t)                                                                        \
    _Pragma("unroll") for (int nf = 0; nf < 4; nf++)                                        \
    _Pragma("unroll") for (int kk = 0; kk < 2; kk++)                                        \
        bk[nf * 2 + kk] = *(const short8*)&Bpk[((size_t)((wn * 4 + nf) * (K / 32)           \
                                               + (t) * 2 + kk) * 64 + l) * 8];

#define COMPUTE_HALF(bi, bk, mh)                                                            \
    {                                                                                       \
        short8 af[8];                                                                       \
        _Pragma("unroll") for (int mf = 0; mf < 4; mf++)                                    \
        _Pragma("unroll") for (int kk = 0; kk < 2; kk++)                                    \
            af[mf * 2 + kk] = *(const short8*)&Albuf[bi][                                   \
                (wm * 128 + (mh) * 64 + mf * 16 + llo) * 64                                 \
                + (((kk * 4 + lhi) ^ (llo & 7)) * 8)];                                      \
        __builtin_amdgcn_s_setprio(1);                                                      \
        _Pragma("unroll") for (int mf = 0; mf < 4; mf++)                                    \
        _Pragma("unroll") for (int nf = 0; nf < 4; nf++)                                    \
        _Pragma("unroll") for (int kk = 0; kk < 2; kk++)                                    \
            acc[(mh) * 4 + mf][nf] = __builtin_amdgcn_mfma_f32_16x16x32_bf16(               \
                bk[nf * 2 + kk], af[mf * 2 + kk], acc[(mh) * 4 + mf][nf], 0, 0, 0);         \
        __builtin_amdgcn_s_setprio(0);                                                      \
    }

template<int K, bool GATHER, bool RELU, bool FUSE3>
__global__ __launch_bounds__(512, 2) void mlp_gemm(
    const ushort* __restrict__ A, const int* __restrict__ idx,
    const ushort* __restrict__ Bpk, const float* __restrict__ bias,
    const float* __restrict__ W3, const float* __restrict__ b3,
    ushort* __restrict__ outb, float* __restrict__ outf)
{
    constexpr int NK = K / 64;
    __shared__ __align__(16) ushort Albuf[3][256 * 64];   // 96 KB ring
    __shared__ float sc[FUSE3 ? 4 : 1][256][2];

    const int tid = threadIdx.x;
    const int w = tid >> 6, l = tid & 63;
    const int llo = l & 15, lhi = l >> 4;
    const int wm = w >> 2, wn = w & 3;
    const int m0 = blockIdx.x * 256;
    const int swz = 8 * ((l & 7) ^ (l >> 3));   // pre-swizzled source column (elems)

    // per-lane staging row pointers: wave w stages rows w*32..w*32+31, 8 rows/issue
    const ushort* rp0[4]; const ushort* rp1[4];
#pragma unroll
    for (int i = 0; i < 4; i++) {
        int r = m0 + w * 32 + i * 8 + (l >> 3);
        if (GATHER) {
            rp0[i] = A + (size_t)idx[2 * r]     * (K / 2) + swz;
            rp1[i] = A + (size_t)idx[2 * r + 1] * (K / 2) + swz;
        } else {
            rp0[i] = A + (size_t)r * K + swz;
            rp1[i] = rp0[i];
        }
    }

    f32x4 acc[8][4];
#pragma unroll
    for (int a = 0; a < 8; a++)
#pragma unroll
        for (int nf = 0; nf < 4; nf++) acc[a][nf] = {0.f, 0.f, 0.f, 0.f};

    short8 bk0[8], bk1[8];

    auto stageA = [&](int bi, int t) {
#pragma unroll
        for (int i = 0; i < 4; i++) {
            const ushort* src;
            if (GATHER) src = ((t < NK / 2) ? rp0[i] : rp1[i]) + ((t * 64) & (K / 2 - 1));
            else        src = rp0[i] + t * 64;
            gload_lds16(src, &Albuf[bi][(w * 32 + i * 8) * 64]);
        }
    };

    // prologue: A for tiles 0,1 staged; B for tile 0 to regs; keep A(1) in flight
    stageA(0, 0);
    LOADB(bk0, 0)
    stageA(1, 1);
    __builtin_amdgcn_sched_barrier(0);
    asm volatile("s_waitcnt vmcnt(4)" ::: "memory");
    __builtin_amdgcn_s_barrier();
    __builtin_amdgcn_sched_barrier(0);

#pragma unroll
    for (int t = 0; t < NK; t++) {
        if (t + 1 < NK) {
            if (t & 1) { LOADB(bk0, t + 1) } else { LOADB(bk1, t + 1) }
        }
        if (t + 2 < NK) stageA((t + 2) % 3, t + 2);
        if (t & 1) { COMPUTE_HALF(t % 3, bk1, 0) COMPUTE_HALF(t % 3, bk1, 1) }
        else       { COMPUTE_HALF(t % 3, bk0, 0) COMPUTE_HALF(t % 3, bk0, 1) }
        if (t + 1 < NK) {
            __builtin_amdgcn_sched_barrier(0);
            if (t + 2 < NK) { asm volatile("s_waitcnt vmcnt(12)" ::: "memory"); }
            else            { asm volatile("s_waitcnt vmcnt(0)"  ::: "memory"); }
            __builtin_amdgcn_s_barrier();
            __builtin_amdgcn_sched_barrier(0);
        }
    }

    // ---------------- epilogue ----------------
    if (!FUSE3) {
        float4 bv[4];
#pragma unroll
        for (int nf = 0; nf < 4; nf++)
            bv[nf] = *(const float4*)&bias[wn * 64 + nf * 16 + lhi * 4];
#pragma unroll
        for (int a = 0; a < 8; a++) {
            int row = m0 + wm * 128 + (a >> 2) * 64 + (a & 3) * 16 + llo;
#pragma unroll
            for (int nf = 0; nf < 4; nf++) {
                int col = wn * 64 + nf * 16 + lhi * 4;
                float v0 = acc[a][nf][0] + bv[nf].x;
                float v1 = acc[a][nf][1] + bv[nf].y;
                float v2 = acc[a][nf][2] + bv[nf].z;
                float v3 = acc[a][nf][3] + bv[nf].w;
                if (RELU) {
                    v0 = fmaxf(v0, 0.f); v1 = fmaxf(v1, 0.f);
                    v2 = fmaxf(v2, 0.f); v3 = fmaxf(v3, 0.f);
                }
                ushort4 o;
                o.x = f2bf(v0); o.y = f2bf(v1); o.z = f2bf(v2); o.w = f2bf(v3);
                *(ushort4*)&outb[(size_t)row * 256 + col] = o;
            }
        }
    } else {
        float p0[8], p1[8];
#pragma unroll
        for (int a = 0; a < 8; a++) { p0[a] = 0.f; p1[a] = 0.f; }
#pragma unroll
        for (int nf = 0; nf < 4; nf++) {
            int colb = wn * 64 + nf * 16 + lhi * 4;
            float4 b2v = *(const float4*)&bias[colb];
            float2 w3a = ((const float2*)W3)[colb + 0];
            float2 w3b = ((const float2*)W3)[colb + 1];
            float2 w3c = ((const float2*)W3)[colb + 2];
            float2 w3d = ((const float2*)W3)[colb + 3];
#pragma unroll
            for (int a = 0; a < 8; a++) {
                float v0 = fmaxf(acc[a][nf][0] + b2v.x, 0.f);
                float v1 = fmaxf(acc[a][nf][1] + b2v.y, 0.f);
                float v2 = fmaxf(acc[a][nf][2] + b2v.z, 0.f);
                float v3 = fmaxf(acc[a][nf][3] + b2v.w, 0.f);
                p0[a] += v0 * w3a.x + v1 * w3b.x + v2 * w3c.x + v3 * w3d.x;
                p1[a] += v0 * w3a.y + v1 * w3b.y + v2 * w3c.y + v3 * w3d.y;
            }
        }
#pragma unroll
        for (int a = 0; a < 8; a++) {
            p0[a] += __shfl_xor(p0[a], 16); p0[a] += __shfl_xor(p0[a], 32);
            p1[a] += __shfl_xor(p1[a], 16); p1[a] += __shfl_xor(p1[a], 32);
        }
        if (lhi == 0) {
#pragma unroll
            for (int a = 0; a < 8; a++) {
                int r = wm * 128 + (a >> 2) * 64 + (a & 3) * 16 + llo;
                sc[wn][r][0] = p0[a];
                sc[wn][r][1] = p1[a];
            }
        }
        __syncthreads();
        {
            int row = tid >> 1, j = tid & 1;
            float s = b3[j] + sc[0][row][j] + sc[1][row][j] + sc[2][row][j] + sc[3][row][j];
            outf[(size_t)(m0 + row) * 2 + j] = s;
        }
    }
}

// ---------------- launch ----------------

extern "C" void kernel_launch(void* const* d_in, const int* in_sizes, int n_in,
                              void* d_out, int out_size, void* d_ws, size_t ws_size,
                              hipStream_t stream) {
    const float* node_feat = (const float*)d_in[0];
    const int* edge_candidate = (const int*)d_in[1];
    const int* nnodes = (const int*)d_in[2];
    const int* ncand = (const int*)d_in[3];
    const float* W_enc = (const float*)d_in[4];
    const float* b_enc = (const float*)d_in[5];
    const float* W1 = (const float*)d_in[6];
    const float* b1 = (const float*)d_in[7];
    const float* W2 = (const float*)d_in[8];
    const float* b2 = (const float*)d_in[9];
    const float* W3 = (const float*)d_in[10];
    const float* b3 = (const float*)d_in[11];

    const int D = 256, H = 256, K1 = 512;
    const int G = in_sizes[2];            // 64
    const int TOTN = in_sizes[0] / D;     // 32768
    const int E = in_sizes[1] / 2;        // 131072
    const int ENS = in_sizes[11];         // 2

    char* wsb = (char*)d_ws;
    size_t off = 0;
    auto alloc = [&](size_t bytes) -> void* {
        void* p = wsb + off;
        off += (bytes + 255) & ~(size_t)255;
        return p;
    };
    ushort* nf_bf = (ushort*)alloc((size_t)TOTN * D * 2);
    ushort* x_bf  = (ushort*)alloc((size_t)TOTN * D * 2);
    ushort* h1    = (ushort*)alloc((size_t)E * H * 2);
    ushort* pkE   = (ushort*)alloc((size_t)D * D * 2);
    ushort* pk1   = (ushort*)alloc((size_t)K1 * H * 2);
    ushort* pk2   = (ushort*)alloc((size_t)H * H * 2);
    int* idxb     = (int*)alloc((size_t)E * 2 * 4);

    float* scores_out = (float*)d_out;
    float* idx_out = scores_out + (size_t)E * ENS;

    // prep
    conv_bf16_k<<<2048, 256, 0, stream>>>(node_feat, nf_bf, TOTN * D / 4);
    pack_b_k<<<(256 * 256 + 255) / 256, 256, 0, stream>>>(W_enc, pkE, 256);
    pack_b_k<<<(256 * 512 + 255) / 256, 256, 0, stream>>>(W1, pk1, 512);
    pack_b_k<<<(256 * 256 + 255) / 256, 256, 0, stream>>>(W2, pk2, 256);
    index_k<<<(E + 255) / 256, 256, 0, stream>>>(edge_candidate, nnodes, ncand, G, E, idxb, idx_out);

    // encoder: x = nf @ W_enc + b_enc
    mlp_gemm<256, false, false, false><<<TOTN / 256, 512, 0, stream>>>(
        nf_bf, nullptr, pkE, b_enc, nullptr, nullptr, x_bf, nullptr);

    // layer 1 (gather fused): h1 = relu(concat(x[i0],x[i1]) @ W1 + b1)
    mlp_gemm<512, true, true, false><<<E / 256, 512, 0, stream>>>(
        x_bf, idxb, pk1, b1, nullptr, nullptr, h1, nullptr);

    // layer 2 + 3 fused: scores = relu(h1 @ W2 + b2) @ W3 + b3
    mlp_gemm<256, false, false, true><<<E / 256, 512, 0, stream>>>(
        h1, nullptr, pk2, b2, W3, b3, nullptr, scores_out);
}

// Round 6
// 94.842 us; speedup vs baseline: 1.5625x; 1.2258x over previous
//
#include <hip/hip_runtime.h>
#include <hip/hip_bf16.h>

typedef short short8 __attribute__((ext_vector_type(8)));
typedef float f32x4 __attribute__((ext_vector_type(4)));

__device__ __forceinline__ ushort f2bf(float f) {
    union { float f; unsigned u; } v; v.f = f;
    unsigned r = v.u + 0x7fff + ((v.u >> 16) & 1);
    return (ushort)(r >> 16);
}

__device__ __forceinline__ void gload_lds16(const void* g, void* l) {
    __builtin_amdgcn_global_load_lds((const __attribute__((address_space(1))) void*)g,
                                     (__attribute__((address_space(3))) void*)l, 16, 0, 0);
}

// ---------------- prep kernels ----------------

__global__ void conv_bf16_k(const float* __restrict__ in, ushort* __restrict__ out, int n4) {
    int i = blockIdx.x * blockDim.x + threadIdx.x;
    int stride = gridDim.x * blockDim.x;
    for (int j = i; j < n4; j += stride) {
        float4 v = ((const float4*)in)[j];
        ushort4 o;
        o.x = f2bf(v.x); o.y = f2bf(v.y); o.z = f2bf(v.z); o.w = f2bf(v.w);
        ((ushort4*)out)[j] = o;
    }
}

// Wc[k][n] (k<256: We@W1a, k>=256: We@W1b), block 512 computes bc = b1 + be@(W1a+W1b)
__global__ void wc_k(const float* __restrict__ We, const float* __restrict__ be,
                     const float* __restrict__ W1, const float* __restrict__ b1,
                     float* __restrict__ Wc, float* __restrict__ bc) {
    int n = threadIdx.x;
    int k = blockIdx.x;
    if (k < 512) {
        const float* werow = We + (size_t)(k & 255) * 256;
        const float* w1col = W1 + ((k >> 8) ? 256 * 256 : 0);
        float acc = 0.f;
#pragma unroll 4
        for (int d = 0; d < 256; d++)
            acc += werow[d] * w1col[(size_t)d * 256 + n];
        Wc[(size_t)k * 256 + n] = acc;
    } else {
        float acc = b1[n];
#pragma unroll 4
        for (int d = 0; d < 256; d++)
            acc += be[d] * (W1[(size_t)d * 256 + n] + W1[(size_t)(d + 256) * 256 + n]);
        bc[n] = acc;
    }
}

// W [K][256] row-major f32 -> packed MFMA B-fragments, per-wave-contiguous:
// out[((F*(K/32)+S)*64 + l)*8 + j] = bf16(W[k][n]),  n=F*16+(l&15), k=S*32+(l>>4)*8+j
__global__ void pack_b_k(const float* __restrict__ W, ushort* __restrict__ out, int K) {
    int id = blockIdx.x * blockDim.x + threadIdx.x;
    if (id >= 256 * K) return;
    int j = id & 7;
    int l = (id >> 3) & 63;
    int S = (id >> 9) % (K / 32);
    int F = id / (512 * (K / 32));
    int n = F * 16 + (l & 15);
    int k = S * 32 + (l >> 4) * 8 + j;
    out[id] = f2bf(W[(size_t)k * 256 + n]);
}

// prefix scan of nnodes/ncand in-block (G<=256), then global index build
__global__ void index_k(const int* __restrict__ ec,
                        const int* __restrict__ nnodes, const int* __restrict__ ncand,
                        int G, int E,
                        int* __restrict__ idx, float* __restrict__ out_idx) {
    __shared__ int snoff[257];
    __shared__ int seoff[257];
    if (threadIdx.x == 0) {
        int a = 0, b = 0;
        for (int g = 0; g < G; g++) {
            snoff[g] = a; a += nnodes[g];
            b += ncand[g]; seoff[g] = b;
        }
    }
    __syncthreads();
    int e = blockIdx.x * blockDim.x + threadIdx.x;
    if (e >= E) return;
    int lo = 0, hi = G - 1;
    while (lo < hi) {
        int mid = (lo + hi) >> 1;
        if (seoff[mid] > e) hi = mid; else lo = mid + 1;
    }
    int off = snoff[lo];
    int g0 = ec[2 * e] + off, g1 = ec[2 * e + 1] + off;
    idx[2 * e] = g0; idx[2 * e + 1] = g1;
    out_idx[2 * e] = (float)g0; out_idx[2 * e + 1] = (float)g1;
}

// ---------------- fused MLP: scores = relu(relu(gath(nf)@Wc+bc)@W2+b2)@W3+b3 ----------------
// BM=128 edges/block, 1024 threads = 16 waves (2 wm x 8 wn), per-wave 64x32 output.
// Phase 1: K=512 gather-GEMM, 3-deep LDS ring (swizzled via pre-swizzled global src),
//          B-fragments (packed Wc) in registers, counted vmcnt at tile boundaries.
// h1 -> LDS (aliases ring). Phase 2: K=256 from LDS, barrier-free. Fused W3 epilogue.

// B-fragment loads: F = wn*2+nf, layout from pack_b_k
#define LOADB(bk, Bp, KDIV32, t)                                                            \
    _Pragma("unroll") for (int nf = 0; nf < 2; nf++)                                        \
    _Pragma("unroll") for (int kk = 0; kk < 2; kk++)                                        \
        bk[nf * 2 + kk] = *(const short8*)&Bp[((size_t)((wn * 2 + nf) * (KDIV32)            \
                                               + (t) * 2 + kk) * 64 + l) * 8];

// phase-1 compute: A-frags from ring buffer bi (XOR-swizzled chunks)
#define COMPUTE1(bi, bk)                                                                    \
    {                                                                                       \
        short8 af[8];                                                                       \
        _Pragma("unroll") for (int mf = 0; mf < 4; mf++)                                    \
        _Pragma("unroll") for (int kk = 0; kk < 2; kk++)                                    \
            af[mf * 2 + kk] = *(const short8*)&ring[(bi) * 8192 +                           \
                (wm * 64 + mf * 16 + llo) * 64 + (((kk * 4 + lhi) ^ (llo & 7)) * 8)];       \
        __builtin_amdgcn_s_setprio(1);                                                      \
        _Pragma("unroll") for (int mf = 0; mf < 4; mf++)                                    \
        _Pragma("unroll") for (int nf = 0; nf < 2; nf++)                                    \
        _Pragma("unroll") for (int kk = 0; kk < 2; kk++)                                    \
            acc[mf][nf] = __builtin_amdgcn_mfma_f32_16x16x32_bf16(                          \
                bk[nf * 2 + kk], af[mf * 2 + kk], acc[mf][nf], 0, 0, 0);                    \
        __builtin_amdgcn_s_setprio(0);                                                      \
    }

// phase-2 compute: A-frags from h1 LDS (chunk c2 = t2*8 + kk*4 + lhi, low-3 XOR row&7)
#define COMPUTE2(t2, bk)                                                                    \
    {                                                                                       \
        short8 af[8];                                                                       \
        _Pragma("unroll") for (int mf = 0; mf < 4; mf++)                                    \
        _Pragma("unroll") for (int kk = 0; kk < 2; kk++)                                    \
            af[mf * 2 + kk] = *(const short8*)&h1lds[                                       \
                (wm * 64 + mf * 16 + llo) * 256 +                                           \
                (((t2) * 8 | ((kk * 4 + lhi) ^ (llo & 7))) * 8)];                           \
        __builtin_amdgcn_s_setprio(1);                                                      \
        _Pragma("unroll") for (int mf = 0; mf < 4; mf++)                                    \
        _Pragma("unroll") for (int nf = 0; nf < 2; nf++)                                    \
        _Pragma("unroll") for (int kk = 0; kk < 2; kk++)                                    \
            acc[mf][nf] = __builtin_amdgcn_mfma_f32_16x16x32_bf16(                          \
                bk[nf * 2 + kk], af[mf * 2 + kk], acc[mf][nf], 0, 0, 0);                    \
        __builtin_amdgcn_s_setprio(0);                                                      \
    }

#define TILE_BARRIER(n)                                                                     \
    __builtin_amdgcn_sched_barrier(0);                                                      \
    asm volatile("s_waitcnt vmcnt(" #n ")" ::: "memory");                                   \
    __builtin_amdgcn_s_barrier();                                                           \
    __builtin_amdgcn_sched_barrier(0);

__global__ __launch_bounds__(1024, 4) void fused_mlp(
    const ushort* __restrict__ nf_bf, const int* __restrict__ idx,
    const ushort* __restrict__ pk1, const float* __restrict__ bc,
    const ushort* __restrict__ pk2, const float* __restrict__ b2,
    const float* __restrict__ W3, const float* __restrict__ b3,
    float* __restrict__ scores)
{
    __shared__ __align__(16) ushort smem[36864];   // 72 KB: ring(48K) aliased by h1(64K), sc at +64K
    ushort* ring = smem;
    ushort* h1lds = smem;
    float* sc = (float*)&smem[32768];              // [8][128][2]

    const int tid = threadIdx.x;
    const int w = tid >> 6, l = tid & 63;
    const int llo = l & 15, lhi = l >> 4;
    const int wm = w >> 3, wn = w & 7;
    const int work = ((blockIdx.x & 7) << 7) + (blockIdx.x >> 3);   // chunked XCD swizzle
    const int m0 = work * 128;

    // staging: each thread loads one row-slice; row = tid>>3, swizzled col chunk
    const int srow = tid >> 3;
    const int swz = 8 * ((l & 7) ^ ((l >> 3) & 7));
    const ushort* rp0 = nf_bf + (size_t)idx[2 * (m0 + srow) + 0] * 256 + swz;
    const ushort* rp1 = nf_bf + (size_t)idx[2 * (m0 + srow) + 1] * 256 + swz;

    f32x4 acc[4][2];
#pragma unroll
    for (int mf = 0; mf < 4; mf++)
#pragma unroll
        for (int nf = 0; nf < 2; nf++) acc[mf][nf] = {0.f, 0.f, 0.f, 0.f};

    short8 bkA[4], bkB[4];

    // stageA(buf, t): one gload_lds16 per thread; wave w covers rows w*8..w*8+7
    auto stageA = [&](int bi, int t) {
        const ushort* src = ((t < 4) ? rp0 : rp1) + ((t & 3) * 64);
        gload_lds16(src, &ring[bi * 8192 + w * 512]);
    };

    // ---- prologue ----
    stageA(0, 0);            // 1
    LOADB(bkA, pk1, 16, 0)   // +4 = 5
    stageA(1, 1);            // +1 = 6
    TILE_BARRIER(5)          // stage(0) complete

    // ---- phase 1: 8 K-tiles ----
#pragma unroll
    for (int t = 0; t < 8; t++) {
        if (t + 1 < 8) {
            if (t & 1) { LOADB(bkA, pk1, 16, t + 1) } else { LOADB(bkB, pk1, 16, t + 1) }
        }
        if (t + 2 < 8) stageA((t + 2) % 3, t + 2);
        if (t & 1) COMPUTE1(t % 3, bkB)
        else       COMPUTE1(t % 3, bkA)
        if (t < 6)      { TILE_BARRIER(5) }
        else if (t == 6){ TILE_BARRIER(4) }
    }

    // prefetch phase-2 B tile 0 while epilogue runs
    LOADB(bkA, pk2, 8, 0)
    __syncthreads();   // all ring reads done; safe to overwrite with h1

    // ---- epilogue 1: h1 = relu(acc + bc) -> LDS (bf16, XOR-swizzled chunks) ----
    {
#pragma unroll
        for (int nf = 0; nf < 2; nf++) {
            int colb = wn * 32 + nf * 16 + lhi * 4;
            float4 bv = *(const float4*)&bc[colb];
            int c = colb >> 3;              // global 8-elem chunk
            int coff = colb & 7;            // 0 or 4
#pragma unroll
            for (int mf = 0; mf < 4; mf++) {
                int row = wm * 64 + mf * 16 + llo;
                float v0 = fmaxf(acc[mf][nf][0] + bv.x, 0.f);
                float v1 = fmaxf(acc[mf][nf][1] + bv.y, 0.f);
                float v2 = fmaxf(acc[mf][nf][2] + bv.z, 0.f);
                float v3 = fmaxf(acc[mf][nf][3] + bv.w, 0.f);
                ushort4 o;
                o.x = f2bf(v0); o.y = f2bf(v1); o.z = f2bf(v2); o.w = f2bf(v3);
                int cs = (c & 24) | ((c & 7) ^ (row & 7));
                *(ushort4*)&h1lds[row * 256 + cs * 8 + coff] = o;
            }
        }
    }
    __syncthreads();   // h1 visible

    // reset acc for phase 2
#pragma unroll
    for (int mf = 0; mf < 4; mf++)
#pragma unroll
        for (int nf = 0; nf < 2; nf++) acc[mf][nf] = {0.f, 0.f, 0.f, 0.f};

    // ---- phase 2: 4 K-tiles from LDS, barrier-free ----
#pragma unroll
    for (int t2 = 0; t2 < 4; t2++) {
        if (t2 + 1 < 4) {
            if (t2 & 1) { LOADB(bkA, pk2, 8, t2 + 1) } else { LOADB(bkB, pk2, 8, t2 + 1) }
        }
        if (t2 & 1) COMPUTE2(t2, bkB)
        else        COMPUTE2(t2, bkA)
    }

    // ---- epilogue 2: scores = relu(acc + b2) @ W3 + b3 ----
    float p0[4], p1[4];
#pragma unroll
    for (int mf = 0; mf < 4; mf++) { p0[mf] = 0.f; p1[mf] = 0.f; }
#pragma unroll
    for (int nf = 0; nf < 2; nf++) {
        int colb = wn * 32 + nf * 16 + lhi * 4;
        float4 b2v = *(const float4*)&b2[colb];
        float2 w3a = ((const float2*)W3)[colb + 0];
        float2 w3b = ((const float2*)W3)[colb + 1];
        float2 w3c = ((const float2*)W3)[colb + 2];
        float2 w3d = ((const float2*)W3)[colb + 3];
#pragma unroll
        for (int mf = 0; mf < 4; mf++) {
            float v0 = fmaxf(acc[mf][nf][0] + b2v.x, 0.f);
            float v1 = fmaxf(acc[mf][nf][1] + b2v.y, 0.f);
            float v2 = fmaxf(acc[mf][nf][2] + b2v.z, 0.f);
            float v3 = fmaxf(acc[mf][nf][3] + b2v.w, 0.f);
            p0[mf] += v0 * w3a.x + v1 * w3b.x + v2 * w3c.x + v3 * w3d.x;
            p1[mf] += v0 * w3a.y + v1 * w3b.y + v2 * w3c.y + v3 * w3d.y;
        }
    }
#pragma unroll
    for (int mf = 0; mf < 4; mf++) {
        p0[mf] += __shfl_xor(p0[mf], 16); p0[mf] += __shfl_xor(p0[mf], 32);
        p1[mf] += __shfl_xor(p1[mf], 16); p1[mf] += __shfl_xor(p1[mf], 32);
    }
    if (l < 16) {
#pragma unroll
        for (int mf = 0; mf < 4; mf++) {
            int r = wm * 64 + mf * 16 + l;
            sc[(wn * 128 + r) * 2 + 0] = p0[mf];
            sc[(wn * 128 + r) * 2 + 1] = p1[mf];
        }
    }
    __syncthreads();
    if (tid < 256) {
        int row = tid >> 1, j = tid & 1;
        float s = b3[j];
#pragma unroll
        for (int q = 0; q < 8; q++) s += sc[(q * 128 + row) * 2 + j];
        scores[(size_t)(m0 + row) * 2 + j] = s;
    }
}

// ---------------- launch ----------------

extern "C" void kernel_launch(void* const* d_in, const int* in_sizes, int n_in,
                              void* d_out, int out_size, void* d_ws, size_t ws_size,
                              hipStream_t stream) {
    const float* node_feat = (const float*)d_in[0];
    const int* edge_candidate = (const int*)d_in[1];
    const int* nnodes = (const int*)d_in[2];
    const int* ncand = (const int*)d_in[3];
    const float* W_enc = (const float*)d_in[4];
    const float* b_enc = (const float*)d_in[5];
    const float* W1 = (const float*)d_in[6];
    const float* b1 = (const float*)d_in[7];
    const float* W2 = (const float*)d_in[8];
    const float* b2 = (const float*)d_in[9];
    const float* W3 = (const float*)d_in[10];
    const float* b3 = (const float*)d_in[11];

    const int D = 256;
    const int G = in_sizes[2];            // 64
    const int TOTN = in_sizes[0] / D;     // 32768
    const int E = in_sizes[1] / 2;        // 131072
    const int ENS = in_sizes[11];         // 2

    char* wsb = (char*)d_ws;
    size_t off = 0;
    auto alloc = [&](size_t bytes) -> void* {
        void* p = wsb + off;
        off += (bytes + 255) & ~(size_t)255;
        return p;
    };
    ushort* nf_bf = (ushort*)alloc((size_t)TOTN * D * 2);
    float*  Wc    = (float*)alloc((size_t)512 * 256 * 4);
    float*  bc    = (float*)alloc(256 * 4);
    ushort* pk1   = (ushort*)alloc((size_t)512 * 256 * 2);
    ushort* pk2   = (ushort*)alloc((size_t)256 * 256 * 2);
    int* idxb     = (int*)alloc((size_t)E * 2 * 4);

    float* scores_out = (float*)d_out;
    float* idx_out = scores_out + (size_t)E * ENS;

    // prep
    conv_bf16_k<<<2048, 256, 0, stream>>>(node_feat, nf_bf, TOTN * D / 4);
    wc_k<<<513, 256, 0, stream>>>(W_enc, b_enc, W1, b1, Wc, bc);
    pack_b_k<<<(256 * 512) / 256, 256, 0, stream>>>(Wc, pk1, 512);
    pack_b_k<<<(256 * 256) / 256, 256, 0, stream>>>(W2, pk2, 256);
    index_k<<<(E + 255) / 256, 256, 0, stream>>>(edge_candidate, nnodes, ncand, G, E, idxb, idx_out);

    // fused L1+L2+L3
    fused_mlp<<<E / 128, 1024, 0, stream>>>(nf_bf, idxb, pk1, bc, pk2, b2, W3, b3, scores_out);
}

// Round 7
// 81.712 us; speedup vs baseline: 1.8136x; 1.1607x over previous
//
#include <hip/hip_runtime.h>
#include <hip/hip_bf16.h>

typedef short short8 __attribute__((ext_vector_type(8)));
typedef float f32x4 __attribute__((ext_vector_type(4)));

__device__ __forceinline__ ushort f2bf(float f) {
    union { float f; unsigned u; } v; v.f = f;
    unsigned r = v.u + 0x7fff + ((v.u >> 16) & 1);
    return (ushort)(r >> 16);
}

__device__ __forceinline__ void gload_lds16(const void* g, void* l) {
    __builtin_amdgcn_global_load_lds((const __attribute__((address_space(1))) void*)g,
                                     (__attribute__((address_space(3))) void*)l, 16, 0, 0);
}

// ---------------- merged prep kernel ----------------
// roles by blockIdx: [0,2048) conv nf->bf16 | [2048,2560) index | [2560,2816) pack W2
// [2816,3329) wc: Wc=[We@W1a;We@W1b] written DIRECTLY in packed pk1 layout; +bc block.

__global__ __launch_bounds__(256) void prep_k(
    const float* __restrict__ node_feat, ushort* __restrict__ nf_bf, int n4,
    const int* __restrict__ ec, const int* __restrict__ nnodes, const int* __restrict__ ncand,
    int G, int E, int* __restrict__ idxb, float* __restrict__ out_idx,
    const float* __restrict__ W2, ushort* __restrict__ pk2,
    const float* __restrict__ We, const float* __restrict__ be,
    const float* __restrict__ W1, const float* __restrict__ b1,
    ushort* __restrict__ pk1, float* __restrict__ bc)
{
    const int b = blockIdx.x;
    if (b < 2048) {
        // ---- conv fp32 -> bf16 ----
        int i = b * 256 + threadIdx.x;
        const int stride = 2048 * 256;
        for (int j = i; j < n4; j += stride) {
            float4 v = ((const float4*)node_feat)[j];
            ushort4 o;
            o.x = f2bf(v.x); o.y = f2bf(v.y); o.z = f2bf(v.z); o.w = f2bf(v.w);
            ((ushort4*)nf_bf)[j] = o;
        }
    } else if (b < 2560) {
        // ---- index build ----
        __shared__ int snoff[257];
        __shared__ int seoff[257];
        if (threadIdx.x == 0) {
            int a = 0, c = 0;
            for (int g = 0; g < G; g++) {
                snoff[g] = a; a += nnodes[g];
                c += ncand[g]; seoff[g] = c;
            }
        }
        __syncthreads();
        int e = (b - 2048) * 256 + threadIdx.x;
        if (e >= E) return;
        int lo = 0, hi = G - 1;
        while (lo < hi) {
            int mid = (lo + hi) >> 1;
            if (seoff[mid] > e) hi = mid; else lo = mid + 1;
        }
        int off = snoff[lo];
        int g0 = ec[2 * e] + off, g1 = ec[2 * e + 1] + off;
        idxb[2 * e] = g0; idxb[2 * e + 1] = g1;
        out_idx[2 * e] = (float)g0; out_idx[2 * e + 1] = (float)g1;
    } else if (b < 2816) {
        // ---- pack W2 [256][256] -> pk2 (K=256, K/32=8) ----
        int id = (b - 2560) * 256 + threadIdx.x;
        int j = id & 7;
        int l = (id >> 3) & 63;
        int S = (id >> 9) & 7;
        int F = id >> 12;
        int n = F * 16 + (l & 15);
        int k = S * 32 + (l >> 4) * 8 + j;
        pk2[id] = f2bf(W2[(size_t)k * 256 + n]);
    } else {
        // ---- wc: row k of Wc computed and written packed into pk1 (K=512) ----
        int k = b - 2816;          // 0..512
        int n = threadIdx.x;
        if (k < 512) {
            const float* werow = We + (size_t)(k & 255) * 256;
            const float* w1col = W1 + ((k >> 8) ? 256 * 256 : 0);
            float acc = 0.f;
#pragma unroll 4
            for (int d = 0; d < 256; d++)
                acc += werow[d] * w1col[(size_t)d * 256 + n];
            int j = k & 7;
            int S = k >> 5;
            int F = n >> 4;
            int l = ((k >> 3) & 3) * 16 + (n & 15);
            pk1[((size_t)(F * 16 + S) * 64 + l) * 8 + j] = f2bf(acc);
        } else {
            float acc = b1[n];
#pragma unroll 4
            for (int d = 0; d < 256; d++)
                acc += be[d] * (W1[(size_t)d * 256 + n] + W1[(size_t)(d + 256) * 256 + n]);
            bc[n] = acc;
        }
    }
}

// ---------------- fused MLP: scores = relu(relu(gath(nf)@Wc+bc)@W2+b2)@W3+b3 ----------------
// BM=128 edges/block, 1024 threads = 16 waves (2 wm x 8 wn), per-wave 64x32 output.
// Phase 1: K=512 gather-GEMM, 4-deep LDS ring (swizzled via pre-swizzled global src),
//          B-fragments (packed) in registers, counted vmcnt at tile boundaries (~3-tile cover).
// h1 -> LDS (aliases ring). Phase 2: K=256 from LDS, barrier-free. Fused W3 epilogue.

#define LOADB(bk, Bp, KDIV32, t)                                                            \
    _Pragma("unroll") for (int nf = 0; nf < 2; nf++)                                        \
    _Pragma("unroll") for (int kk = 0; kk < 2; kk++)                                        \
        bk[nf * 2 + kk] = *(const short8*)&Bp[((size_t)((wn * 2 + nf) * (KDIV32)            \
                                               + (t) * 2 + kk) * 64 + l) * 8];

#define COMPUTE1(bi, bk)                                                                    \
    {                                                                                       \
        short8 af[8];                                                                       \
        _Pragma("unroll") for (int mf = 0; mf < 4; mf++)                                    \
        _Pragma("unroll") for (int kk = 0; kk < 2; kk++)                                    \
            af[mf * 2 + kk] = *(const short8*)&ring[(bi) * 8192 +                           \
                (wm * 64 + mf * 16 + llo) * 64 + (((kk * 4 + lhi) ^ (llo & 7)) * 8)];       \
        __builtin_amdgcn_s_setprio(1);                                                      \
        _Pragma("unroll") for (int mf = 0; mf < 4; mf++)                                    \
        _Pragma("unroll") for (int nf = 0; nf < 2; nf++)                                    \
        _Pragma("unroll") for (int kk = 0; kk < 2; kk++)                                    \
            acc[mf][nf] = __builtin_amdgcn_mfma_f32_16x16x32_bf16(                          \
                bk[nf * 2 + kk], af[mf * 2 + kk], acc[mf][nf], 0, 0, 0);                    \
        __builtin_amdgcn_s_setprio(0);                                                      \
    }

#define COMPUTE2(t2, bk)                                                                    \
    {                                                                                       \
        short8 af[8];                                                                       \
        _Pragma("unroll") for (int mf = 0; mf < 4; mf++)                                    \
        _Pragma("unroll") for (int kk = 0; kk < 2; kk++)                                    \
            af[mf * 2 + kk] = *(const short8*)&h1lds[                                       \
                (wm * 64 + mf * 16 + llo) * 256 +                                           \
                (((t2) * 8 | ((kk * 4 + lhi) ^ (llo & 7))) * 8)];                           \
        __builtin_amdgcn_s_setprio(1);                                                      \
        _Pragma("unroll") for (int mf = 0; mf < 4; mf++)                                    \
        _Pragma("unroll") for (int nf = 0; nf < 2; nf++)                                    \
        _Pragma("unroll") for (int kk = 0; kk < 2; kk++)                                    \
            acc[mf][nf] = __builtin_amdgcn_mfma_f32_16x16x32_bf16(                          \
                bk[nf * 2 + kk], af[mf * 2 + kk], acc[mf][nf], 0, 0, 0);                    \
        __builtin_amdgcn_s_setprio(0);                                                      \
    }

#define TILE_BARRIER(n)                                                                     \
    __builtin_amdgcn_sched_barrier(0);                                                      \
    asm volatile("s_waitcnt vmcnt(" #n ")" ::: "memory");                                   \
    __builtin_amdgcn_s_barrier();                                                           \
    __builtin_amdgcn_sched_barrier(0);

__global__ __launch_bounds__(1024, 4) void fused_mlp(
    const ushort* __restrict__ nf_bf, const int* __restrict__ idx,
    const ushort* __restrict__ pk1, const float* __restrict__ bc,
    const ushort* __restrict__ pk2, const float* __restrict__ b2,
    const float* __restrict__ W3, const float* __restrict__ b3,
    float* __restrict__ scores)
{
    __shared__ __align__(16) ushort smem[36864];   // 72 KB: ring 4x16K aliased by h1(64K), sc at +64K
    ushort* ring = smem;
    ushort* h1lds = smem;
    float* sc = (float*)&smem[32768];              // [8][128][2]

    const int tid = threadIdx.x;
    const int w = tid >> 6, l = tid & 63;
    const int llo = l & 15, lhi = l >> 4;
    const int wm = w >> 3, wn = w & 7;
    const int work = ((blockIdx.x & 7) << 7) + (blockIdx.x >> 3);   // chunked XCD swizzle
    const int m0 = work * 128;

    // staging: each thread loads one row-slice; row = tid>>3, swizzled col chunk
    const int srow = tid >> 3;
    const int swz = 8 * ((l & 7) ^ ((l >> 3) & 7));
    const int2 ip = *(const int2*)&idx[2 * (m0 + srow)];
    const ushort* rp0 = nf_bf + (size_t)ip.x * 256 + swz;
    const ushort* rp1 = nf_bf + (size_t)ip.y * 256 + swz;

    f32x4 acc[4][2];
#pragma unroll
    for (int mf = 0; mf < 4; mf++)
#pragma unroll
        for (int nf = 0; nf < 2; nf++) acc[mf][nf] = {0.f, 0.f, 0.f, 0.f};

    short8 bkA[4], bkB[4];

    auto stageA = [&](int bi, int t) {
        const ushort* src = ((t < 4) ? rp0 : rp1) + ((t & 3) * 64);
        gload_lds16(src, &ring[bi * 8192 + w * 512]);
    };

    // ---- prologue: stage tiles 0,1,2 ----
    stageA(0, 0);            // 1
    LOADB(bkA, pk1, 16, 0)   // +4 = 5
    stageA(1, 1);            // 6
    stageA(2, 2);            // 7
    TILE_BARRIER(6)          // stage(0) retired

    // ---- phase 1: 8 K-tiles, 4-deep ring ----
#pragma unroll
    for (int t = 0; t < 8; t++) {
        if (t + 1 < 8) {
            if (t & 1) { LOADB(bkA, pk1, 16, t + 1) } else { LOADB(bkB, pk1, 16, t + 1) }
        }
        if (t + 3 < 8) stageA((t + 3) & 3, t + 3);
        if (t & 1) COMPUTE1(t & 3, bkB)
        else       COMPUTE1(t & 3, bkA)
        if (t == 0)      { TILE_BARRIER(6) }
        else if (t <= 4) { TILE_BARRIER(10) }
        else if (t == 5) { TILE_BARRIER(9) }
        else if (t == 6) { TILE_BARRIER(8) }
    }

    // prefetch phase-2 B tile 0 while epilogue runs
    LOADB(bkA, pk2, 8, 0)
    __syncthreads();   // all ring reads done; safe to overwrite with h1

    // ---- epilogue 1: h1 = relu(acc + bc) -> LDS (bf16, XOR-swizzled chunks) ----
    {
#pragma unroll
        for (int nf = 0; nf < 2; nf++) {
            int colb = wn * 32 + nf * 16 + lhi * 4;
            float4 bv = *(const float4*)&bc[colb];
            int c = colb >> 3;
            int coff = colb & 7;
#pragma unroll
            for (int mf = 0; mf < 4; mf++) {
                int row = wm * 64 + mf * 16 + llo;
                float v0 = fmaxf(acc[mf][nf][0] + bv.x, 0.f);
                float v1 = fmaxf(acc[mf][nf][1] + bv.y, 0.f);
                float v2 = fmaxf(acc[mf][nf][2] + bv.z, 0.f);
                float v3 = fmaxf(acc[mf][nf][3] + bv.w, 0.f);
                ushort4 o;
                o.x = f2bf(v0); o.y = f2bf(v1); o.z = f2bf(v2); o.w = f2bf(v3);
                int cs = (c & 24) | ((c & 7) ^ (row & 7));
                *(ushort4*)&h1lds[row * 256 + cs * 8 + coff] = o;
            }
        }
    }
    __syncthreads();   // h1 visible

#pragma unroll
    for (int mf = 0; mf < 4; mf++)
#pragma unroll
        for (int nf = 0; nf < 2; nf++) acc[mf][nf] = {0.f, 0.f, 0.f, 0.f};

    // ---- phase 2: 4 K-tiles from LDS, barrier-free ----
#pragma unroll
    for (int t2 = 0; t2 < 4; t2++) {
        if (t2 + 1 < 4) {
            if (t2 & 1) { LOADB(bkA, pk2, 8, t2 + 1) } else { LOADB(bkB, pk2, 8, t2 + 1) }
        }
        if (t2 & 1) COMPUTE2(t2, bkB)
        else        COMPUTE2(t2, bkA)
    }

    // ---- epilogue 2: scores = relu(acc + b2) @ W3 + b3 ----
    float p0[4], p1[4];
#pragma unroll
    for (int mf = 0; mf < 4; mf++) { p0[mf] = 0.f; p1[mf] = 0.f; }
#pragma unroll
    for (int nf = 0; nf < 2; nf++) {
        int colb = wn * 32 + nf * 16 + lhi * 4;
        float4 b2v = *(const float4*)&b2[colb];
        float2 w3a = ((const float2*)W3)[colb + 0];
        float2 w3b = ((const float2*)W3)[colb + 1];
        float2 w3c = ((const float2*)W3)[colb + 2];
        float2 w3d = ((const float2*)W3)[colb + 3];
#pragma unroll
        for (int mf = 0; mf < 4; mf++) {
            float v0 = fmaxf(acc[mf][nf][0] + b2v.x, 0.f);
            float v1 = fmaxf(acc[mf][nf][1] + b2v.y, 0.f);
            float v2 = fmaxf(acc[mf][nf][2] + b2v.z, 0.f);
            float v3 = fmaxf(acc[mf][nf][3] + b2v.w, 0.f);
            p0[mf] += v0 * w3a.x + v1 * w3b.x + v2 * w3c.x + v3 * w3d.x;
            p1[mf] += v0 * w3a.y + v1 * w3b.y + v2 * w3c.y + v3 * w3d.y;
        }
    }
#pragma unroll
    for (int mf = 0; mf < 4; mf++) {
        p0[mf] += __shfl_xor(p0[mf], 16); p0[mf] += __shfl_xor(p0[mf], 32);
        p1[mf] += __shfl_xor(p1[mf], 16); p1[mf] += __shfl_xor(p1[mf], 32);
    }
    if (l < 16) {
#pragma unroll
        for (int mf = 0; mf < 4; mf++) {
            int r = wm * 64 + mf * 16 + l;
            sc[(wn * 128 + r) * 2 + 0] = p0[mf];
            sc[(wn * 128 + r) * 2 + 1] = p1[mf];
        }
    }
    __syncthreads();
    if (tid < 256) {
        int row = tid >> 1, j = tid & 1;
        float s = b3[j];
#pragma unroll
        for (int q = 0; q < 8; q++) s += sc[(q * 128 + row) * 2 + j];
        scores[(size_t)(m0 + row) * 2 + j] = s;
    }
}

// ---------------- launch ----------------

extern "C" void kernel_launch(void* const* d_in, const int* in_sizes, int n_in,
                              void* d_out, int out_size, void* d_ws, size_t ws_size,
                              hipStream_t stream) {
    const float* node_feat = (const float*)d_in[0];
    const int* edge_candidate = (const int*)d_in[1];
    const int* nnodes = (const int*)d_in[2];
    const int* ncand = (const int*)d_in[3];
    const float* W_enc = (const float*)d_in[4];
    const float* b_enc = (const float*)d_in[5];
    const float* W1 = (const float*)d_in[6];
    const float* b1 = (const float*)d_in[7];
    const float* W2 = (const float*)d_in[8];
    const float* b2 = (const float*)d_in[9];
    const float* W3 = (const float*)d_in[10];
    const float* b3 = (const float*)d_in[11];

    const int D = 256;
    const int G = in_sizes[2];            // 64
    const int TOTN = in_sizes[0] / D;     // 32768
    const int E = in_sizes[1] / 2;        // 131072
    const int ENS = in_sizes[11];         // 2

    char* wsb = (char*)d_ws;
    size_t off = 0;
    auto alloc = [&](size_t bytes) -> void* {
        void* p = wsb + off;
        off += (bytes + 255) & ~(size_t)255;
        return p;
    };
    ushort* nf_bf = (ushort*)alloc((size_t)TOTN * D * 2);
    ushort* pk1   = (ushort*)alloc((size_t)512 * 256 * 2);
    ushort* pk2   = (ushort*)alloc((size_t)256 * 256 * 2);
    float*  bc    = (float*)alloc(256 * 4);
    int* idxb     = (int*)alloc((size_t)E * 2 * 4);

    float* scores_out = (float*)d_out;
    float* idx_out = scores_out + (size_t)E * ENS;

    // merged prep: conv | index | pack W2 | wc->pk1 + bc
    prep_k<<<3329, 256, 0, stream>>>(
        node_feat, nf_bf, TOTN * D / 4,
        edge_candidate, nnodes, ncand, G, E, idxb, idx_out,
        W2, pk2,
        W_enc, b_enc, W1, b1, pk1, bc);

    // fused L1+L2+L3
    fused_mlp<<<E / 128, 1024, 0, stream>>>(nf_bf, idxb, pk1, bc, pk2, b2, W3, b3, scores_out);
}